// Round 6
// baseline (261.072 us; speedup 1.0000x reference)
//
#include <hip/hip_runtime.h>

// ---------------------------------------------------------------------------
// LuminanceAwareMHSA: B=4, C=256, H=W=48 (N=2304), HEADS=8, DH=32, HID=128
// Round 12:
//   k6: split-K 2->3 (grid 54x8x4 = 1728 blocks, 12 tiles each) and P-scratch
//       shared between qf phases (write->read->PV per qf; DS wave-in-order).
//       LDS 32->24KB. Inner math byte-identical to the proven round-7 kernel.
//       Third O partial aliases the dead xt buffer (no new workspace).
//   k7: combines 3 partials through the MFMA C chain.
//   k_prep fusion, k5/k7 reg double-buffering kept from round 11.
// ---------------------------------------------------------------------------

#define NSP 2304
#define WID 48

typedef __attribute__((ext_vector_type(4))) float  fvec4;
typedef __attribute__((ext_vector_type(2))) unsigned int uvec2;
typedef __attribute__((ext_vector_type(4))) unsigned int uvec4;
typedef __attribute__((ext_vector_type(8))) short  short8;   // 8 bf16 (4 VGPRs)
typedef __attribute__((ext_vector_type(4))) float  f32x4;    // MFMA C/D

__device__ inline unsigned short f2bf(float f){
  unsigned int u = __builtin_bit_cast(unsigned int, f);
  u += 0x7fffu + ((u >> 16) & 1u);           // RNE
  return (unsigned short)(u >> 16);
}
__device__ inline unsigned pack2bf(float a, float b){
#if __has_builtin(__builtin_amdgcn_cvt_pk_bf16_f32)
  typedef __attribute__((ext_vector_type(2))) __bf16 bf16x2;
  bf16x2 r = __builtin_amdgcn_cvt_pk_bf16_f32(a, b);
  return __builtin_bit_cast(unsigned, r);
#else
  return (unsigned)f2bf(a) | ((unsigned)f2bf(b) << 16);
#endif
}

// ---------------------------------------------------------------------------
// k_prep: fused prep. blockIdx.x ranges:
//   [0,4)       : luma job (b = bx)
//   [4,1604)    : weight cast job
//   [1604,2180) : xt transpose job
__global__ __launch_bounds__(256) void k_prep(const float* __restrict__ c2w,
    const float* __restrict__ wq, const float* __restrict__ wk, const float* __restrict__ wv_,
    const float* __restrict__ wproj, const float* __restrict__ x,
    const float* __restrict__ rgb, const float* __restrict__ alphaP,
    unsigned short* __restrict__ wtb, unsigned short* __restrict__ wqkvb,
    unsigned short* __restrict__ wprojb, unsigned short* __restrict__ xt,
    float* __restrict__ luma_n, float* __restrict__ bias_a,
    float* __restrict__ hm_sum, unsigned short* __restrict__ h1p){
  __shared__ __align__(16) float sm[5120];   // 20480 B union
  int bx = blockIdx.x, t = threadIdx.x;
  if (bx < 4){
    // ---------------- luma job ----------------
    int b = bx;
    float* ly  = sm;
    float* ll  = sm + NSP;
    float* red = sm + 2*NSP;
    float* red2= sm + 2*NSP + 256;
    {
      const uvec4 z = {0u,0u,0u,0u};
      for (int j = t; j < 196*16; j += 256){
        int cell = j >> 4, q = j & 15;
        int r, c;
        if (cell < 50)      { r = 0;           c = cell; }
        else if (cell < 100){ r = 49;          c = cell - 50; }
        else if (cell < 148){ r = cell - 99;   c = 0; }
        else                { r = cell - 147;  c = 49; }
        *(uvec4*)(h1p + ((size_t)(b*2500 + r*50 + c))*128 + q*8) = z;
      }
    }
    const float* rp = rgb + b*3*NSP;
    float lmin = 1e30f, lmax = -1e30f;
    for (int i = t; i < NSP; i += 256){
      float y = 0.299f*rp[i] + 0.587f*rp[NSP+i] + 0.114f*rp[2*NSP+i];
      ly[i] = y; lmin = fminf(lmin, y); lmax = fmaxf(lmax, y);
    }
    red[t] = lmin; red2[t] = lmax;
    __syncthreads();
    for (int s = 128; s > 0; s >>= 1){
      if (t < s){ red[t] = fminf(red[t], red[t+s]); red2[t] = fmaxf(red2[t], red2[t+s]); }
      __syncthreads();
    }
    float mn = red[0], mx = red2[0];
    float inv = 1.0f / (mx - mn + 1e-6f);
    for (int i = t; i < NSP; i += 256){
      float v = (ly[i] - mn) * inv;
      ll[i] = v;
      luma_n[b*NSP + i] = v;
    }
    if (t < 128) hm_sum[b*128 + t] = 0.f;
    __syncthreads();
    float pr[9]; float psum = 0.f;
    #pragma unroll
    for (int ii = 0; ii < 9; ++ii){
      int n = t + 256*ii;
      int row = n / WID, col = n - row*WID;
      float s2 = 0.f;
      #pragma unroll
      for (int dy = -1; dy <= 1; ++dy)
        #pragma unroll
        for (int dx = -1; dx <= 1; ++dx){
          int r2 = row+dy, c2 = col+dx;
          if (r2 >= 0 && r2 < WID && c2 >= 0 && c2 < WID) s2 += 1.0f - ll[r2*WID + c2];
        }
      pr[ii] = s2 * (1.f/9.f);
      psum += pr[ii];
    }
    __syncthreads();
    red[t] = psum;
    __syncthreads();
    for (int s = 128; s > 0; s >>= 1){
      if (t < s) red[t] += red[t+s];
      __syncthreads();
    }
    float mean = red[0] * (1.f/(float)NSP);
    float alpha = alphaP[0] * 1.4426950408889634f;   // fold log2(e) for exp2
    #pragma unroll
    for (int ii = 0; ii < 9; ++ii){
      int n = t + 256*ii;
      bias_a[b*NSP + n] = alpha * (pr[ii] - mean);
    }
  } else if (bx < 1604){
    // ---------------- weight cast job ----------------
    int idx = (bx - 4)*256 + t;
    if (idx < 147456){
      int ic = idx & 127, rem = idx >> 7;
      int oc = rem & 127, tap = rem >> 7;
      wtb[idx] = f2bf(c2w[(oc*128 + ic)*9 + tap]);
    } else if (idx < 344064){
      int j = idx - 147456;
      int mat = j >> 16, oc_ = j & 65535;
      const float* src = (mat == 0) ? wq : (mat == 1) ? wk : wv_;
      wqkvb[j] = f2bf(src[oc_]);
    } else {
      int j = idx - 344064;
      wprojb[j] = f2bf(wproj[j]);
    }
  } else {
    // ---------------- xt transpose job ----------------
    int j = bx - 1604;                 // 0..575
    int nt = j % 36, cc = (j / 36) & 3, b = j / 144;
    unsigned short* tb = (unsigned short*)sm;   // 64*72 shorts = 9216 B
    int cl0 = t >> 4;           // 0..15
    int nl0 = (t & 15) * 4;     // 0..60
    #pragma unroll
    for (int ps_ = 0; ps_ < 4; ++ps_){
      int cl = cl0 + ps_*16;
      fvec4 v = *(const fvec4*)(x + ((size_t)(b*256 + cc*64 + cl))*NSP + nt*64 + nl0);
      #pragma unroll
      for (int i = 0; i < 4; ++i) tb[(nl0+i)*72 + cl] = f2bf(v[i]);
    }
    __syncthreads();
    int nl = t >> 2, cg = (t & 3) * 16;
    uvec4 u0 = *(const uvec4*)&tb[nl*72 + cg];
    uvec4 u1 = *(const uvec4*)&tb[nl*72 + cg + 8];
    unsigned short* dst = xt + ((size_t)(b*NSP + nt*64 + nl))*256 + cc*64 + cg;
    *(uvec4*)dst = u0;
    *(uvec4*)(dst + 8) = u1;
  }
}

// ---------------------------------------------------------------------------
// K2: conv1 3x3, 1 -> 128 channels, relu -> bf16 padded h1p[b][50*50][128].
__global__ void k2_conv1(const float* __restrict__ luma_n, const float* __restrict__ c1w,
                         const float* __restrict__ c1b, unsigned short* __restrict__ h1p){
  int nt = blockIdx.x, ocg = blockIdx.y, b = blockIdx.z, t = threadIdx.x;
  __shared__ float wsm[32*9];
  __shared__ float bsm[32];
  for (int i = t; i < 288; i += 256) wsm[i] = c1w[ocg*288 + i];
  if (t < 32) bsm[t] = c1b[ocg*32 + t];
  __syncthreads();
  int n = nt*256 + t;
  int row = n / WID, col = n - row*WID;
  const float* lp = luma_n + b*NSP;
  float lv[9];
  int k = 0;
  #pragma unroll
  for (int dy = -1; dy <= 1; ++dy)
    #pragma unroll
    for (int dx = -1; dx <= 1; ++dx, ++k){
      int r2 = row+dy, c2 = col+dx;
      lv[k] = (r2 >= 0 && r2 < WID && c2 >= 0 && c2 < WID) ? lp[r2*WID + c2] : 0.f;
    }
  unsigned int packed[16];
  #pragma unroll
  for (int oc2 = 0; oc2 < 16; ++oc2){
    float a0 = bsm[oc2*2], a1 = bsm[oc2*2+1];
    #pragma unroll
    for (int q = 0; q < 9; ++q){
      a0 += wsm[(oc2*2)*9 + q] * lv[q];
      a1 += wsm[(oc2*2+1)*9 + q] * lv[q];
    }
    packed[oc2] = pack2bf(fmaxf(a0, 0.f), fmaxf(a1, 0.f));
  }
  unsigned short* dst = h1p + ((size_t)(b*2500 + (row+1)*50 + (col+1)))*128 + ocg*32;
  #pragma unroll
  for (int q4 = 0; q4 < 4; ++q4)
    *(uvec4*)(dst + q4*8) = *(uvec4*)&packed[q4*4];
}

// ---------------------------------------------------------------------------
// K3: conv2 128->128 as 9 shifted MFMA GEMMs + relu + column-sum -> hm_sum.
__global__ __launch_bounds__(256) void k3_conv2(const unsigned short* __restrict__ h1p,
    const unsigned short* __restrict__ wtb, const float* __restrict__ c2b,
    float* __restrict__ hm_sum){
  int row = blockIdx.x, mh = blockIdx.y, b = blockIdx.z;
  int t = threadIdx.x, wv = t >> 6, lane = t & 63;
  int lq = lane >> 4, lc = lane & 15;
  int ocb = mh*64 + wv*16;
  const f32x4 z4 = {0.f, 0.f, 0.f, 0.f};
  f32x4 C[3] = {z4, z4, z4};
  const unsigned short* hbase = h1p + (size_t)b*2500*128;
  #pragma unroll
  for (int tap = 0; tap < 9; ++tap){
    int dy = tap/3 - 1, dx = tap%3 - 1;
    const unsigned short* wrow = wtb + (tap*128 + ocb + lc)*128 + lq*8;
    const unsigned short* hrow = hbase + ((row+dy+1)*50 + (dx+1) + lc)*128 + lq*8;
    #pragma unroll
    for (int kc = 0; kc < 4; ++kc){
      short8 aW = *(const short8*)(wrow + kc*32);
      #pragma unroll
      for (int ntp = 0; ntp < 3; ++ntp){
        short8 bH = *(const short8*)(hrow + ntp*16*128 + kc*32);
        C[ntp] = __builtin_amdgcn_mfma_f32_16x16x32_bf16(aW, bH, C[ntp], 0, 0, 0);
      }
    }
  }
  float s[4];
  #pragma unroll
  for (int r = 0; r < 4; ++r){
    float bias = c2b[ocb + lq*4 + r];
    float v = 0.f;
    #pragma unroll
    for (int ntp = 0; ntp < 3; ++ntp) v += fmaxf(C[ntp][r] + bias, 0.f);
    v += __shfl_xor(v, 1, 64);
    v += __shfl_xor(v, 2, 64);
    v += __shfl_xor(v, 4, 64);
    v += __shfl_xor(v, 8, 64);
    s[r] = v;
  }
  if (lc == 0){
    #pragma unroll
    for (int r = 0; r < 4; ++r)
      atomicAdd(&hm_sum[b*128 + ocb + lq*4 + r], s[r]);
  }
}

// ---------------------------------------------------------------------------
// K4: FiLM params. film[(m6*4 + b)*256 + o]
__global__ void k4_film(const float* __restrict__ hm_sum,
  const float* w0, const float* b0, const float* w1, const float* b1,
  const float* w2, const float* b2, const float* w3, const float* b3,
  const float* w4, const float* b4, const float* w5, const float* b5,
  float* __restrict__ film){
  __shared__ float hs[128];
  int bb = blockIdx.x & 3, m6 = blockIdx.x >> 2, t = threadIdx.x;
  if (t < 128) hs[t] = hm_sum[bb*128 + t] * (1.f/(float)NSP);
  __syncthreads();
  const float* wm[6] = {w0,w1,w2,w3,w4,w5};
  const float* bm[6] = {b0,b1,b2,b3,b4,b5};
  const float* w = wm[m6];
  int o = t;
  float a = bm[m6][o];
  for (int h2 = 0; h2 < 128; ++h2) a += hs[h2] * w[o*128 + h2];
  film[blockIdx.x*256 + t] = a;
}

// ---------------------------------------------------------------------------
// K5: QKV via bf16 MFMA, kc loop register double-buffered.
// grid (36 nt, 6 ot, 4 b); wave: 32 o x 64 n. FiLM epilogue; emits q_t/k_t
// [B,8,N,32] bf16 (SCALE*log2e in q), v_b [B,256,N] bf16.
__global__ __launch_bounds__(256) void k5_qkv(const unsigned short* __restrict__ xt,
    const unsigned short* __restrict__ wqkvb,
    const float* __restrict__ bq, const float* __restrict__ bk, const float* __restrict__ bv,
    const float* __restrict__ film,
    unsigned short* __restrict__ q_t, unsigned short* __restrict__ k_t,
    unsigned short* __restrict__ v_b){
  int nt = blockIdx.x, ot = blockIdx.y, b = blockIdx.z;
  int t = threadIdx.x, wv = t >> 6, lane = t & 63;
  int lq = lane >> 4, lc = lane & 15;
  int p = ot >> 1;
  int omb = (ot & 1)*128 + wv*32;
  const f32x4 z4 = {0.f, 0.f, 0.f, 0.f};
  f32x4 acc[2][4];
  #pragma unroll
  for (int oh = 0; oh < 2; ++oh)
    #pragma unroll
    for (int nq = 0; nq < 4; ++nq) acc[oh][nq] = z4;

  const unsigned short* wbp = wqkvb + p*65536 + (omb + lc)*256 + lq*8;
  const unsigned short* xbp = xt + ((size_t)(b*NSP + nt*64 + lc))*256 + lq*8;

  short8 aW0[2], aW1[2], bX0[4], bX1[4];
  auto loadW = [&](short8 (&W)[2], int kc){
    #pragma unroll
    for (int oh = 0; oh < 2; ++oh) W[oh] = *(const short8*)(wbp + oh*16*256 + kc*32);
  };
  auto loadX = [&](short8 (&X)[4], int kc){
    #pragma unroll
    for (int nq = 0; nq < 4; ++nq) X[nq] = *(const short8*)(xbp + (size_t)nq*16*256 + kc*32);
  };
  auto mm = [&](short8 (&W)[2], short8 (&X)[4]){
    #pragma unroll
    for (int oh = 0; oh < 2; ++oh)
      #pragma unroll
      for (int nq = 0; nq < 4; ++nq)
        acc[oh][nq] = __builtin_amdgcn_mfma_f32_16x16x32_bf16(W[oh], X[nq], acc[oh][nq], 0, 0, 0);
  };
  loadW(aW0, 0); loadX(bX0, 0);
  for (int kc2 = 0; kc2 < 4; ++kc2){
    loadW(aW1, kc2*2+1); loadX(bX1, kc2*2+1);
    mm(aW0, bX0);
    int kn = (kc2*2+2) & 7;          // 8 wraps to 0: harmless warm reload
    loadW(aW0, kn); loadX(bX0, kn);
    mm(aW1, bX1);
  }

  const float* bvec = (p == 0) ? bq : (p == 1) ? bk : bv;
  int hq = omb >> 5;                       // head (uniform per wave), p<2 only
  unsigned short* qk = (p == 0) ? q_t : k_t;
  #pragma unroll
  for (int oh = 0; oh < 2; ++oh){
    fvec4 g4 = *(const fvec4*)(film + (2*p*4 + b)*256 + omb + oh*16 + lq*4);
    fvec4 t4 = *(const fvec4*)(film + ((2*p+1)*4 + b)*256 + omb + oh*16 + lq*4);
    fvec4 z4b = *(const fvec4*)(bvec + omb + oh*16 + lq*4);
    #pragma unroll
    for (int nq = 0; nq < 4; ++nq){
      int n = nt*64 + nq*16 + lc;
      float v0 = g4[0]*(acc[oh][nq][0] + z4b[0]) + t4[0];
      float v1 = g4[1]*(acc[oh][nq][1] + z4b[1]) + t4[1];
      float v2 = g4[2]*(acc[oh][nq][2] + z4b[2]) + t4[2];
      float v3 = g4[3]*(acc[oh][nq][3] + z4b[3]) + t4[3];
      if (p == 0){
        const float sc = 0.17677669529663687f * 1.4426950408889634f;  // SCALE*log2e
        v0 *= sc; v1 *= sc; v2 *= sc; v3 *= sc;
      }
      if (p < 2){
        uvec2 u;
        u.x = pack2bf(v0, v1);
        u.y = pack2bf(v2, v3);
        *(uvec2*)(qk + ((size_t)((b*8 + hq)*NSP + n))*32 + oh*16 + lq*4) = u;
      } else {
        int om = omb + oh*16 + lq*4;
        v_b[((size_t)(b*256 + om + 0))*NSP + n] = f2bf(v0);
        v_b[((size_t)(b*256 + om + 1))*NSP + n] = f2bf(v1);
        v_b[((size_t)(b*256 + om + 2))*NSP + n] = f2bf(v2);
        v_b[((size_t)(b*256 + om + 3))*NSP + n] = f2bf(v3);
      }
    }
  }
}

// ---------------------------------------------------------------------------
// K6 (round 12): flash attention, split-K=3, block-cooperative staged K/V
// (round-7 proven reg-stage + swizzled ds_write, double-buffered, ONE
// barrier/iter). P-scratch SHARED between qf phases: per qf {S-MFMAs + exp2 +
// pack + ps write; ps read + PV MFMAs} - DS ops are wave-in-order so the
// qf=1 writes cannot pass the qf=0 reads. LDS 24KB (16K K/V + 8K ps).
// grid (54 = 18 qblk x 3 split, 8 h, 4 b), 12 key-tiles per block.
__global__ __launch_bounds__(256, 4) void k6_attn(const unsigned short* __restrict__ q_t,
    const unsigned short* __restrict__ k_t, const unsigned short* __restrict__ v_b,
    const float* __restrict__ bias_a,
    unsigned short* __restrict__ o0, unsigned short* __restrict__ o1,
    unsigned short* __restrict__ o2,
    float* __restrict__ l0, float* __restrict__ l1, float* __restrict__ l2){
  int bx = blockIdx.x, h = blockIdx.y, b = blockIdx.z;
  int qblk = bx / 3, s = bx - qblk*3;
  unsigned short* op = (s == 0) ? o0 : (s == 1) ? o1 : o2;
  float* lp = (s == 0) ? l0 : (s == 1) ? l1 : l2;
  int t = threadIdx.x, wv = t >> 6, lane = t & 63;
  int lq = lane >> 4, lc = lane & 15;
  int bh = b*8 + h;
  int nb0 = qblk*128 + wv*32;
  const f32x4 z4 = {0.f, 0.f, 0.f, 0.f};
  int ms = s*768;                           // 12 tiles of 64 keys per split

  __shared__ unsigned short Kb[2][64*32];   // [key][dh], 16B col c stored at c^((row>>1)&3)
  __shared__ unsigned short Vb[2][32*64];   // [dh][key], 16B col c stored at c^(row&7)
  __shared__ float ps[4][512];              // per-wave P scratch (2KB), shared across qf

  // --- staging addresses (16B per thread per tile) ---
  const unsigned short* kg = k_t + ((size_t)bh*NSP + ms + (t>>2))*32 + (t&3)*8;
  const unsigned short* vg = v_b + ((size_t)(b*256 + h*32 + (t>>3)))*NSP + ms + (t&7)*8;
  int krow = t >> 2;
  unsigned short* kw = &Kb[0][krow*32 + (((t&3) ^ ((krow>>1)&3))*8)];
  int vrow = t >> 3;
  unsigned short* vw = &Vb[0][vrow*64 + (((t&7) ^ (vrow&7))*8)];

  // --- per-wave fragment read offsets (swizzled) ---
  int kcol = (lq ^ ((lc>>1)&3))*8;          // Kb col slot for aK
  int sxm = ((lc&7)<<2) | (((lc>>3)&1)<<1); // P scratch dword swizzle
  int wbase = lc*32;

  const float* brow = bias_a + b*NSP + ms;
  fvec4 c0r[4];
  #pragma unroll
  for (int g = 0; g < 4; ++g) c0r[g] = *(const fvec4*)(brow + g*16 + lq*4);

  short8 aQ[2];
  #pragma unroll
  for (int qf = 0; qf < 2; ++qf)
    aQ[qf] = *(const short8*)(q_t + ((size_t)(bh*NSP + nb0 + qf*16 + lc))*32 + lq*8);

  uvec4 gKr = *(const uvec4*)kg;
  uvec4 gVr = *(const uvec4*)vg;

  const uvec4 onesu = {0x3F803F80u, 0x3F803F80u, 0x3F803F80u, 0x3F803F80u};
  const short8 aOnes = __builtin_bit_cast(short8, onesu);

  f32x4 O[2][2]; f32x4 Ol[2];
  #pragma unroll
  for (int qf = 0; qf < 2; ++qf){
    Ol[qf] = z4; O[qf][0] = z4; O[qf][1] = z4;
  }
  float* myps = ps[wv];

  for (int it = 0; it < 12; ++it){
    int buf = it & 1;
    // stage tile it into LDS (waits vmcnt on gKr/gVr, loaded last iter)
    *(uvec4*)(kw + buf*2048) = gKr;
    *(uvec4*)(vw + buf*2048) = gVr;
    __syncthreads();
    // issue next-tile loads immediately; consumed by next iter's ds_write
    if (it < 11){
      gKr = *(const uvec4*)(kg + (it+1)*2048);
      gVr = *(const uvec4*)(vg + (it+1)*64);
    }
    const unsigned short* kb = Kb[buf];
    const unsigned short* vb = Vb[buf];
    short8 aK[4], aV[2][2];
    #pragma unroll
    for (int g = 0; g < 4; ++g)
      aK[g] = *(const short8*)(kb + (g*16 + lc)*32 + kcol);
    #pragma unroll
    for (int dhg = 0; dhg < 2; ++dhg)
      #pragma unroll
      for (int mh = 0; mh < 2; ++mh)
        aV[dhg][mh] = *(const short8*)(vb + (dhg*16 + lc)*64 + (((mh*4 + lq) ^ (lc&7))*8));
    // per-qf: S (MFMA + exp2 + pack + ps write) then PV (ps read + MFMAs).
    #pragma unroll
    for (int qf = 0; qf < 2; ++qf){
      #pragma unroll
      for (int g = 0; g < 4; ++g){
        f32x4 S = __builtin_amdgcn_mfma_f32_16x16x32_bf16(aK[g], aQ[qf], c0r[g], 0, 0, 0);
        uvec2 w2;
        w2.x = pack2bf(__builtin_amdgcn_exp2f(S[0]), __builtin_amdgcn_exp2f(S[1]));
        w2.y = pack2bf(__builtin_amdgcn_exp2f(S[2]), __builtin_amdgcn_exp2f(S[3]));
        *(uvec2*)&myps[wbase + ((g*8 + lq*2) ^ sxm)] = w2;
      }
      // prefetch next-tile bias after c0r's last use (qf==1 S-phase)
      if (qf == 1 && it < 11){
        #pragma unroll
        for (int g = 0; g < 4; ++g)
          c0r[g] = *(const fvec4*)(brow + (it+1)*64 + g*16 + lq*4);
      }
      __builtin_amdgcn_s_setprio(1);
      #pragma unroll
      for (int mh = 0; mh < 2; ++mh){
        int d0 = (mh*16 + lq*4) ^ sxm;
        uvec2 lo = *(const uvec2*)&myps[wbase + d0];
        uvec2 hi = *(const uvec2*)&myps[wbase + (d0 ^ 2)];
        uvec4 up; up.x = lo.x; up.y = lo.y; up.z = hi.x; up.w = hi.y;
        short8 bP = __builtin_bit_cast(short8, up);
        Ol[qf] = __builtin_amdgcn_mfma_f32_16x16x32_bf16(aOnes, bP, Ol[qf], 0, 0, 0);
        #pragma unroll
        for (int dhg = 0; dhg < 2; ++dhg)
          O[qf][dhg] = __builtin_amdgcn_mfma_f32_16x16x32_bf16(aV[dhg][mh], bP, O[qf][dhg], 0, 0, 0);
      }
      __builtin_amdgcn_s_setprio(0);
    }
  }
  // store bf16 O partials [b][n][og] (og = h*32 + d), f32 l partials
  #pragma unroll
  for (int qf = 0; qf < 2; ++qf){
    int nidx = nb0 + qf*16 + lc;
    if (lq == 0) lp[b*NSP + nidx] = Ol[qf][0];
    #pragma unroll
    for (int dh = 0; dh < 2; ++dh){
      uvec2 u;
      u.x = pack2bf(O[qf][dh][0], O[qf][dh][1]);
      u.y = pack2bf(O[qf][dh][2], O[qf][dh][3]);
      *(uvec2*)(op + ((size_t)(b*NSP + nidx))*256 + h*32 + dh*16 + lq*4) = u;
    }
  }
}

// ---------------------------------------------------------------------------
// K7 (round 12): out[c][n] = (sum_o wproj[c][o]*(a0+a1+a2)[o][n]) * rl[n]
// + bproj[c]. bf16 MFMA, kc loop register double-buffered; partials combined
// through the MFMA C chain. grid (72 nt(32 n), 2 ct(128 c), 4 b).
__global__ __launch_bounds__(256) void k7_proj(const unsigned short* __restrict__ a0,
    const unsigned short* __restrict__ a1, const unsigned short* __restrict__ a2,
    const float* __restrict__ l0p, const float* __restrict__ l1p,
    const float* __restrict__ l2p, const unsigned short* __restrict__ wprojb,
    const float* __restrict__ bproj, float* __restrict__ out){
  int nt = blockIdx.x, ct = blockIdx.y, b = blockIdx.z;
  int t = threadIdx.x, wv = t >> 6, lane = t & 63;
  int lq = lane >> 4, lc = lane & 15;
  __shared__ float rls[32];
  if (t < 32) rls[t] = 1.0f / (l0p[b*NSP + nt*32 + t] + l1p[b*NSP + nt*32 + t]
                               + l2p[b*NSP + nt*32 + t]);
  __syncthreads();
  int cb = ct*128 + wv*32;
  const f32x4 z4 = {0.f, 0.f, 0.f, 0.f};
  f32x4 acc[2][2];
  #pragma unroll
  for (int ch = 0; ch < 2; ++ch)
    #pragma unroll
    for (int nq = 0; nq < 2; ++nq) acc[ch][nq] = z4;

  const unsigned short* wpp = wprojb + (cb + lc)*256 + lq*8;
  const unsigned short* a0p = a0 + ((size_t)(b*NSP + nt*32 + lc))*256 + lq*8;
  const unsigned short* a1p = a1 + ((size_t)(b*NSP + nt*32 + lc))*256 + lq*8;
  const unsigned short* a2p = a2 + ((size_t)(b*NSP + nt*32 + lc))*256 + lq*8;

  short8 W0[2], W1[2], B0[3][2], B1[3][2];
  auto loadS = [&](short8 (&W)[2], short8 (&B)[3][2], int kc){
    #pragma unroll
    for (int ch = 0; ch < 2; ++ch) W[ch] = *(const short8*)(wpp + ch*16*256 + kc*32);
    #pragma unroll
    for (int nq = 0; nq < 2; ++nq){
      B[0][nq] = *(const short8*)(a0p + (size_t)nq*16*256 + kc*32);
      B[1][nq] = *(const short8*)(a1p + (size_t)nq*16*256 + kc*32);
      B[2][nq] = *(const short8*)(a2p + (size_t)nq*16*256 + kc*32);
    }
  };
  auto mmS = [&](short8 (&W)[2], short8 (&B)[3][2]){
    #pragma unroll
    for (int src = 0; src < 3; ++src)
      #pragma unroll
      for (int ch = 0; ch < 2; ++ch)
        #pragma unroll
        for (int nq = 0; nq < 2; ++nq)
          acc[ch][nq] = __builtin_amdgcn_mfma_f32_16x16x32_bf16(W[ch], B[src][nq], acc[ch][nq], 0, 0, 0);
  };
  loadS(W0, B0, 0);
  for (int kc2 = 0; kc2 < 4; ++kc2){
    loadS(W1, B1, kc2*2+1);
    mmS(W0, B0);
    int kn = (kc2*2+2) & 7;          // 8 wraps to 0: harmless warm reload
    loadS(W0, B0, kn);
    mmS(W1, B1);
  }

  #pragma unroll
  for (int ch = 0; ch < 2; ++ch){
    #pragma unroll
    for (int nq = 0; nq < 2; ++nq){
      int n = nt*32 + nq*16 + lc;
      float rl = rls[nq*16 + lc];
      #pragma unroll
      for (int r = 0; r < 4; ++r){
        int c = cb + ch*16 + lq*4 + r;
        out[((size_t)(b*256 + c))*NSP + n] = acc[ch][nq][r]*rl + bproj[c];
      }
    }
  }
}

// ---------------------------------------------------------------------------
extern "C" void kernel_launch(void* const* d_in, const int* in_sizes, int n_in,
                              void* d_out, int out_size, void* d_ws, size_t ws_size,
                              hipStream_t stream) {
  const float* x     = (const float*)d_in[0];
  const float* rgb   = (const float*)d_in[1];
  const float* wq    = (const float*)d_in[2];
  const float* bq    = (const float*)d_in[3];
  const float* wk    = (const float*)d_in[4];
  const float* bk    = (const float*)d_in[5];
  const float* wv    = (const float*)d_in[6];
  const float* bv    = (const float*)d_in[7];
  const float* wproj = (const float*)d_in[8];
  const float* bproj = (const float*)d_in[9];
  const float* c1w   = (const float*)d_in[10];
  const float* c1b   = (const float*)d_in[11];
  const float* c2w   = (const float*)d_in[12];
  const float* c2b   = (const float*)d_in[13];
  const float* gq_w  = (const float*)d_in[14];
  const float* gq_b  = (const float*)d_in[15];
  const float* bqf_w = (const float*)d_in[16];
  const float* bqf_b = (const float*)d_in[17];
  const float* gk_w  = (const float*)d_in[18];
  const float* gk_b  = (const float*)d_in[19];
  const float* bkf_w = (const float*)d_in[20];
  const float* bkf_b = (const float*)d_in[21];
  const float* gv_w  = (const float*)d_in[22];
  const float* gv_b  = (const float*)d_in[23];
  const float* bvf_w = (const float*)d_in[24];
  const float* bvf_b = (const float*)d_in[25];
  const float* alphaP= (const float*)d_in[26];

  char* w = (char*)d_ws;
  float* luma_n = (float*)w;            w += 4*NSP*4;             // 36864
  float* bias_a = (float*)w;            w += 4*NSP*4;             // 36864
  float* hm_sum = (float*)w;            w += 512*4;               // 2048
  float* film   = (float*)w;            w += 6*4*256*4;           // 24576
  unsigned short* h1p = (unsigned short*)w; w += 4*2500*128*2;    // 2,560,000 (padded bf16)
  unsigned short* wtb = (unsigned short*)w; w += 9*128*128*2;     // 294,912
  unsigned short* wqkvb = (unsigned short*)w; w += 3*256*256*2;   // 393,216
  unsigned short* wprojb = (unsigned short*)w; w += 256*256*2;    // 131,072
  unsigned short* xt  = (unsigned short*)w; w += (size_t)4*NSP*256*2; // 4,718,592 (o_part2 after k5)
  unsigned short* q_t = (unsigned short*)w; w += (size_t)4*8*NSP*32*2; // 4,718,592
  unsigned short* k_t = (unsigned short*)w; w += (size_t)4*8*NSP*32*2; // 4,718,592
  unsigned short* v_b = (unsigned short*)w; w += (size_t)4*256*NSP*2;  // 4,718,592
  unsigned short* o_part0 = (unsigned short*)w; w += (size_t)4*NSP*256*2; // 4,718,592
  unsigned short* o_part1 = (unsigned short*)w; w += (size_t)4*NSP*256*2; // 4,718,592
  float* l_part0 = (float*)w;           w += 4*NSP*4;             // 36864
  float* l_part1 = (float*)w;           w += 4*NSP*4;             // 36864
  float* l_part2 = (float*)w;           w += 4*NSP*4;             // 36864
  unsigned short* o_part2 = xt;         // alias: xt is dead after k5
  // total ~31.9 MB

  k_prep  <<<2180, 256, 0, stream>>>(c2w, wq, wk, wv, wproj, x, rgb, alphaP,
                                     wtb, wqkvb, wprojb, xt,
                                     luma_n, bias_a, hm_sum, h1p);
  k2_conv1<<<dim3(9,4,4), 256, 0, stream>>>(luma_n, c1w, c1b, h1p);
  k3_conv2<<<dim3(48,2,4), 256, 0, stream>>>(h1p, wtb, c2b, hm_sum);
  k4_film <<<24, 256, 0, stream>>>(hm_sum, gq_w, gq_b, bqf_w, bqf_b,
                                   gk_w, gk_b, bkf_w, bkf_b,
                                   gv_w, gv_b, bvf_w, bvf_b, film);
  k5_qkv  <<<dim3(36,6,4), 256, 0, stream>>>(xt, wqkvb, bq, bk, bv, film,
                                             q_t, k_t, v_b);
  k6_attn <<<dim3(54,8,4), 256, 0, stream>>>(q_t, k_t, v_b, bias_a,
                                             o_part0, o_part1, o_part2,
                                             l_part0, l_part1, l_part2);
  k7_proj <<<dim3(72,2,4), 256, 0, stream>>>(o_part0, o_part1, o_part2,
                                             l_part0, l_part1, l_part2,
                                             wprojb, bproj, (float*)d_out);
}